// Round 21
// baseline (31.225 us; speedup 1.0000x reference)
//
#include <hip/hip_runtime.h>

// out[n,k] = sum_{i,j} x[n,i] * W[k,i,j] * x[n,j]   (N=262144 rows, D=32)
// R21 vs R17/R19/R20 (22.8 plateau): BARRIER-FREE, WAVE-INDEPENDENT.
// All plateau structures shared: block barrier (stage->compute lockstep),
// btab LDS copy, serial prep leg. R19 proved LDS-vs-occupancy trades flat ->
// btab LDS buys nothing over L2 (33KB table is L2-resident per XCD; access
// bt[s*64+lane] is wave-uniform base + lane*16B = perfectly coalesced 1KB).
// Here: NO __syncthreads, NO btab copy. bfrag read from L2 per step; x
// staging is WAVE-LOCAL (wave loads its own 32 rows coalesced, packs,
// ds_writes its private 2.3KB slice, reads back -- same-wave lgkmcnt only).
// 512thr x 1024 blocks (flow), (512,8): ~50 regs -> 32 waves/CU.
// K-loop math identical to R12 lineage (absmax 0.25).
//
// Algorithm: symmetrized circular-diagonal GEMM. p = d*32+i, d=0..16,
// z[n,p] = x[n,i]*x[n,(i+d)&31], Wf[p,k] = W[k,i,j]+W[k,j,i] (d=0 diag,
// d=16 half), K = 528 = 33 MFMA steps of v_mfma_f32_32x32x16_f16.

typedef _Float16 f16x2 __attribute__((ext_vector_type(2)));
typedef _Float16 f16x4 __attribute__((ext_vector_type(4)));
typedef _Float16 f16x8 __attribute__((ext_vector_type(8)));
typedef float    f32x16 __attribute__((ext_vector_type(16)));

static __device__ __forceinline__ unsigned int pk2_f16(float lo, float hi) {
    return __builtin_bit_cast(unsigned int, __builtin_amdgcn_cvt_pkrtz(lo, hi));
}
static __device__ __forceinline__ f16x2 u2h(unsigned int u) {
    return __builtin_bit_cast(f16x2, u);
}
static __device__ __forceinline__ unsigned short f16b(float f) {
    _Float16 h = (_Float16)f;
    return __builtin_bit_cast(unsigned short, h);
}

// ---- prep (R16): one block per k; stage W_k in LDS coalesced, gather ----
__global__ __launch_bounds__(256)
void prep_btab_sym(const float* __restrict__ W, unsigned short* __restrict__ bt) {
    __shared__ float Wlds[1024];                    // 4 KiB = W[k,:,:]
    const int k = blockIdx.x;                       // 0..31
    const int t = threadIdx.x;
    {
        const float4* src = (const float4*)(W + k * 1024);
        ((float4*)Wlds)[t] = src[t];
    }
    __syncthreads();
    if (t < 66) {                                   // 33 n x 2 l-halves
        int n  = t >> 1;
        int lh = t & 1;                             // l = k + lh*32
        int d  = (n == 32) ? 16 : (n >> 1);
        int q  = (n == 32) ? 0  : (n & 1);
        unsigned short v[8];
        #pragma unroll
        for (int b = 0; b < 8; ++b) {
            int i = q * 16 + lh * 8 + b;
            int j = (i + d) & 31;
            float s = (d == 0) ? Wlds[i * 32 + i]
                               : Wlds[i * 32 + j] + Wlds[j * 32 + i];
            v[b] = f16b(s);
        }
        uint4 pk;
        pk.x = (unsigned int)v[0] | ((unsigned int)v[1] << 16);
        pk.y = (unsigned int)v[2] | ((unsigned int)v[3] << 16);
        pk.z = (unsigned int)v[4] | ((unsigned int)v[5] << 16);
        pk.w = (unsigned int)v[6] | ((unsigned int)v[7] << 16);
        ((uint4*)bt)[n * 64 + k + lh * 32] = pk;
    }
}

#define XS 18   // u32 per staged row: odd multiples spread banks; 2-way max

__global__ __launch_bounds__(512, 8)
void quadform_kernel(const float* __restrict__ x,
                     const uint4* __restrict__ bt,
                     float* __restrict__ out) {
    __shared__ __align__(16) unsigned int xstage[256 * XS];   // 18432 B

    const int tid  = threadIdx.x;
    const int lane = tid & 63;
    const int wave = tid >> 6;
    const int hi   = lane >> 5;
    const int rl   = lane & 31;
    const long wrow = (long)blockIdx.x * 256 + wave * 32;   // wave's 32 rows

    // ---- wave-local coalesced x load: 4 float4/lane over the wave's 4KB ----
    const float4* xsrc = (const float4*)(x + wrow * 32);
    float4 v0 = xsrc[lane];
    float4 v1 = xsrc[64 + lane];
    float4 v2 = xsrc[128 + lane];
    float4 v3 = xsrc[192 + lane];

    // ---- pack + stage into the wave's PRIVATE LDS slice (no barrier) ----
    unsigned int* ws = &xstage[wave * 32 * XS];
    #pragma unroll
    for (int c = 0; c < 4; ++c) {
        float4 v = (c == 0) ? v0 : (c == 1) ? v1 : (c == 2) ? v2 : v3;
        int idx = c * 64 + lane;                 // float4 index within wave
        int row = idx >> 3;                      // 8 float4 per row
        int sub = idx & 7;
        uint2 w2;
        w2.x = pk2_f16(v.x, v.y);
        w2.y = pk2_f16(v.z, v.w);
        *(uint2*)&ws[row * XS + sub * 2] = w2;
    }

    // ---- read own row back (same-wave dep: lgkmcnt only), rotate by hi ----
    unsigned int ypk[16];
    {
        unsigned int xpk[16];
        const unsigned int* xr = &ws[rl * XS];
        #pragma unroll
        for (int c = 0; c < 4; ++c) {
            uint4 v = *(const uint4*)(xr + c * 4);
            xpk[c * 4 + 0] = v.x;
            xpk[c * 4 + 1] = v.y;
            xpk[c * 4 + 2] = v.z;
            xpk[c * 4 + 3] = v.w;
        }
        #pragma unroll
        for (int c = 0; c < 16; ++c)
            ypk[c] = hi ? xpk[(c + 4) & 15] : xpk[c];
    }

    f32x16 acc;
    #pragma unroll
    for (int e = 0; e < 16; ++e) acc[e] = 0.0f;

    // ---- K loop: 33 steps; bfrag streamed from L2 (coalesced 1KB/step) ----
    #pragma unroll
    for (int s = 0; s < 33; ++s) {
        const int d   = (s == 32) ? 16 : (s >> 1);
        const int q8  = ((s == 32) ? 0 : (s & 1)) * 8;
        const int dh  = d >> 1;
        const bool od = (d & 1) != 0;
        uint4 bu = bt[s * 64 + lane];
        f16x8 bfrag = __builtin_bit_cast(f16x8, bu);

        f16x2 b0 = od ? u2h(__builtin_amdgcn_perm(ypk[(q8 + 0 + dh + 1) & 15], ypk[(q8 + 0 + dh) & 15], 0x05040302u)) : u2h(ypk[(q8 + 0 + dh) & 15]);
        f16x2 b1 = od ? u2h(__builtin_amdgcn_perm(ypk[(q8 + 1 + dh + 1) & 15], ypk[(q8 + 1 + dh) & 15], 0x05040302u)) : u2h(ypk[(q8 + 1 + dh) & 15]);
        f16x2 b2 = od ? u2h(__builtin_amdgcn_perm(ypk[(q8 + 2 + dh + 1) & 15], ypk[(q8 + 2 + dh) & 15], 0x05040302u)) : u2h(ypk[(q8 + 2 + dh) & 15]);
        f16x2 b3 = od ? u2h(__builtin_amdgcn_perm(ypk[(q8 + 3 + dh + 1) & 15], ypk[(q8 + 3 + dh) & 15], 0x05040302u)) : u2h(ypk[(q8 + 3 + dh) & 15]);
        f16x2 a0 = u2h(ypk[q8 + 0]) * b0;
        f16x2 a1 = u2h(ypk[q8 + 1]) * b1;
        f16x2 a2 = u2h(ypk[q8 + 2]) * b2;
        f16x2 a3 = u2h(ypk[q8 + 3]) * b3;
        f16x4 lo = __builtin_shufflevector(a0, a1, 0, 1, 2, 3);
        f16x4 hf = __builtin_shufflevector(a2, a3, 0, 1, 2, 3);
        f16x8 a  = __builtin_shufflevector(lo, hf, 0, 1, 2, 3, 4, 5, 6, 7);
        acc = __builtin_amdgcn_mfma_f32_32x32x16_f16(a, bfrag, acc, 0, 0, 0);
    }

    // ---- store: one base, 16 constant-offset nontemporal stores ----
    float* ob = out + (wrow + 4 * hi) * 32 + rl;
    #pragma unroll
    for (int e = 0; e < 16; ++e)
        __builtin_nontemporal_store(acc[e], ob + (e & 3) * 32 + (e >> 2) * 256);
}

extern "C" void kernel_launch(void* const* d_in, const int* in_sizes, int n_in,
                              void* d_out, int out_size, void* d_ws, size_t ws_size,
                              hipStream_t stream) {
    const float* x = (const float*)d_in[0];
    const float* W = (const float*)d_in[1];
    float* out = (float*)d_out;
    unsigned short* bt = (unsigned short*)d_ws;    // 33 KiB table

    prep_btab_sym<<<32, 256, 0, stream>>>(W, bt);
    int nrows = in_sizes[0] / 32;          // 262144
    int grid  = nrows / 256;               // 1024 blocks x 512 thr
    quadform_kernel<<<grid, 512, 0, stream>>>(x, (const uint4*)bt, out);
}

// Round 22
// 24.810 us; speedup vs baseline: 1.2586x; 1.2586x over previous
//
#include <hip/hip_runtime.h>

// out[n,k] = sum_{i,j} x[n,i] * W[k,i,j] * x[n,j]   (N=262144 rows, D=32)
// R22: B-TABLE IN REGISTERS. The 528-fragment Wsym table is 16B/lane/step
// -> 33 uint4 = 132 VGPRs holds ALL of B per lane. Deletes: per-step LDS
// B-reads (R17's biggest on-CU term, 5.3us/CU), per-block btab copy, block
// barrier. btab loaded ONCE per wave from L2 (33 coalesced 1KB loads,
// hoisted off the critical path -- unlike R21's in-loop streams, which
// regressed). x staging wave-local (R21 validated). 2 row-tiles/wave:
// state = btab 132 + ypk 32 + acc 32(AGPR, unified) + temps ~= 216 regs
// -> launch_bounds(256,2) (cap 256, no spill), 8 waves/CU, 4096 waves.
// K-loop = pure regs + MFMA + VALU; kernel should approach the ~10.6us
// two-way HBM floor + ~3us on-CU + prep.
// Math byte-identical to R12 lineage (absmax 0.25).
//
// Algorithm: symmetrized circular-diagonal GEMM. p = d*32+i, d=0..16,
// z[n,p] = x[n,i]*x[n,(i+d)&31], Wf[p,k] = W[k,i,j]+W[k,j,i] (d=0 diag,
// d=16 half), K = 528 = 33 MFMA steps of v_mfma_f32_32x32x16_f16.

typedef _Float16 f16x2 __attribute__((ext_vector_type(2)));
typedef _Float16 f16x4 __attribute__((ext_vector_type(4)));
typedef _Float16 f16x8 __attribute__((ext_vector_type(8)));
typedef float    f32x16 __attribute__((ext_vector_type(16)));

static __device__ __forceinline__ unsigned int pk2_f16(float lo, float hi) {
    return __builtin_bit_cast(unsigned int, __builtin_amdgcn_cvt_pkrtz(lo, hi));
}
static __device__ __forceinline__ f16x2 u2h(unsigned int u) {
    return __builtin_bit_cast(f16x2, u);
}
static __device__ __forceinline__ unsigned short f16b(float f) {
    _Float16 h = (_Float16)f;
    return __builtin_bit_cast(unsigned short, h);
}

// ---- prep (R16): one block per k; stage W_k in LDS coalesced, gather ----
__global__ __launch_bounds__(256)
void prep_btab_sym(const float* __restrict__ W, unsigned short* __restrict__ bt) {
    __shared__ float Wlds[1024];                    // 4 KiB = W[k,:,:]
    const int k = blockIdx.x;                       // 0..31
    const int t = threadIdx.x;
    {
        const float4* src = (const float4*)(W + k * 1024);
        ((float4*)Wlds)[t] = src[t];
    }
    __syncthreads();
    if (t < 66) {                                   // 33 n x 2 l-halves
        int n  = t >> 1;
        int lh = t & 1;                             // l = k + lh*32
        int d  = (n == 32) ? 16 : (n >> 1);
        int q  = (n == 32) ? 0  : (n & 1);
        unsigned short v[8];
        #pragma unroll
        for (int b = 0; b < 8; ++b) {
            int i = q * 16 + lh * 8 + b;
            int j = (i + d) & 31;
            float s = (d == 0) ? Wlds[i * 32 + i]
                               : Wlds[i * 32 + j] + Wlds[j * 32 + i];
            v[b] = f16b(s);
        }
        uint4 pk;
        pk.x = (unsigned int)v[0] | ((unsigned int)v[1] << 16);
        pk.y = (unsigned int)v[2] | ((unsigned int)v[3] << 16);
        pk.z = (unsigned int)v[4] | ((unsigned int)v[5] << 16);
        pk.w = (unsigned int)v[6] | ((unsigned int)v[7] << 16);
        ((uint4*)bt)[n * 64 + k + lh * 32] = pk;
    }
}

#define XS 18   // u32 per staged row: 2-way max read aliasing (free)

__global__ __launch_bounds__(256, 2)
void quadform_kernel(const float* __restrict__ x,
                     const uint4* __restrict__ bt,
                     float* __restrict__ out) {
    __shared__ __align__(16) unsigned int xstage[256 * XS];   // 18432 B

    const int tid  = threadIdx.x;
    const int lane = tid & 63;
    const int wave = tid >> 6;
    const int hi   = lane >> 5;
    const int rl   = lane & 31;
    const long wrow = (long)blockIdx.x * 256 + wave * 64;   // wave's 64 rows

    // ---- 1) whole B-table into registers: 33 coalesced 1KB loads ----
    uint4 bf[33];
    #pragma unroll
    for (int s = 0; s < 33; ++s) bf[s] = bt[s * 64 + lane];

    // ---- 2) wave-local coalesced x load: 8 float4/lane = 64 rows ----
    const float4* xsrc = (const float4*)(x + wrow * 32);
    float4 v0 = xsrc[lane];
    float4 v1 = xsrc[64 + lane];
    float4 v2 = xsrc[128 + lane];
    float4 v3 = xsrc[192 + lane];
    float4 v4 = xsrc[256 + lane];
    float4 v5 = xsrc[320 + lane];
    float4 v6 = xsrc[384 + lane];
    float4 v7 = xsrc[448 + lane];

    // ---- 3) pack + stage into the wave's PRIVATE LDS slice (no barrier) ----
    unsigned int* ws = &xstage[wave * 64 * XS];
    #pragma unroll
    for (int c = 0; c < 8; ++c) {
        float4 v = (c == 0) ? v0 : (c == 1) ? v1 : (c == 2) ? v2 :
                   (c == 3) ? v3 : (c == 4) ? v4 : (c == 5) ? v5 :
                   (c == 6) ? v6 : v7;
        int idx = c * 64 + lane;                 // float4 index within wave
        int row = idx >> 3;                      // 8 float4 per row
        int sub = idx & 7;
        uint2 w2;
        w2.x = pk2_f16(v.x, v.y);
        w2.y = pk2_f16(v.z, v.w);
        *(uint2*)&ws[row * XS + sub * 2] = w2;
    }

    // ---- 4) read own 2 rows back (same-wave lgkmcnt), rotate by hi ----
    unsigned int ypk0[16], ypk1[16];
    {
        unsigned int xpk0[16], xpk1[16];
        const unsigned int* xr0 = &ws[rl * XS];
        const unsigned int* xr1 = &ws[(32 + rl) * XS];
        #pragma unroll
        for (int c = 0; c < 4; ++c) {
            uint4 a = *(const uint4*)(xr0 + c * 4);
            uint4 b = *(const uint4*)(xr1 + c * 4);
            xpk0[c * 4 + 0] = a.x; xpk0[c * 4 + 1] = a.y;
            xpk0[c * 4 + 2] = a.z; xpk0[c * 4 + 3] = a.w;
            xpk1[c * 4 + 0] = b.x; xpk1[c * 4 + 1] = b.y;
            xpk1[c * 4 + 2] = b.z; xpk1[c * 4 + 3] = b.w;
        }
        #pragma unroll
        for (int c = 0; c < 16; ++c) {
            ypk0[c] = hi ? xpk0[(c + 4) & 15] : xpk0[c];
            ypk1[c] = hi ? xpk1[(c + 4) & 15] : xpk1[c];
        }
    }

    f32x16 accA, accB;
    #pragma unroll
    for (int e = 0; e < 16; ++e) { accA[e] = 0.0f; accB[e] = 0.0f; }

    // ---- 5) K loop: 33 steps, B from REGISTERS, 2 tiles per step ----
    #pragma unroll
    for (int s = 0; s < 33; ++s) {
        const int d   = (s == 32) ? 16 : (s >> 1);
        const int q8  = ((s == 32) ? 0 : (s & 1)) * 8;
        const int dh  = d >> 1;
        const bool od = (d & 1) != 0;
        f16x8 bfrag = __builtin_bit_cast(f16x8, bf[s]);

        {   // tile 0
            f16x2 b0 = od ? u2h(__builtin_amdgcn_perm(ypk0[(q8 + 0 + dh + 1) & 15], ypk0[(q8 + 0 + dh) & 15], 0x05040302u)) : u2h(ypk0[(q8 + 0 + dh) & 15]);
            f16x2 b1 = od ? u2h(__builtin_amdgcn_perm(ypk0[(q8 + 1 + dh + 1) & 15], ypk0[(q8 + 1 + dh) & 15], 0x05040302u)) : u2h(ypk0[(q8 + 1 + dh) & 15]);
            f16x2 b2 = od ? u2h(__builtin_amdgcn_perm(ypk0[(q8 + 2 + dh + 1) & 15], ypk0[(q8 + 2 + dh) & 15], 0x05040302u)) : u2h(ypk0[(q8 + 2 + dh) & 15]);
            f16x2 b3 = od ? u2h(__builtin_amdgcn_perm(ypk0[(q8 + 3 + dh + 1) & 15], ypk0[(q8 + 3 + dh) & 15], 0x05040302u)) : u2h(ypk0[(q8 + 3 + dh) & 15]);
            f16x2 a0 = u2h(ypk0[q8 + 0]) * b0;
            f16x2 a1 = u2h(ypk0[q8 + 1]) * b1;
            f16x2 a2 = u2h(ypk0[q8 + 2]) * b2;
            f16x2 a3 = u2h(ypk0[q8 + 3]) * b3;
            f16x4 lo = __builtin_shufflevector(a0, a1, 0, 1, 2, 3);
            f16x4 hf = __builtin_shufflevector(a2, a3, 0, 1, 2, 3);
            f16x8 a  = __builtin_shufflevector(lo, hf, 0, 1, 2, 3, 4, 5, 6, 7);
            accA = __builtin_amdgcn_mfma_f32_32x32x16_f16(a, bfrag, accA, 0, 0, 0);
        }
        {   // tile 1 (same bfrag register)
            f16x2 b0 = od ? u2h(__builtin_amdgcn_perm(ypk1[(q8 + 0 + dh + 1) & 15], ypk1[(q8 + 0 + dh) & 15], 0x05040302u)) : u2h(ypk1[(q8 + 0 + dh) & 15]);
            f16x2 b1 = od ? u2h(__builtin_amdgcn_perm(ypk1[(q8 + 1 + dh + 1) & 15], ypk1[(q8 + 1 + dh) & 15], 0x05040302u)) : u2h(ypk1[(q8 + 1 + dh) & 15]);
            f16x2 b2 = od ? u2h(__builtin_amdgcn_perm(ypk1[(q8 + 2 + dh + 1) & 15], ypk1[(q8 + 2 + dh) & 15], 0x05040302u)) : u2h(ypk1[(q8 + 2 + dh) & 15]);
            f16x2 b3 = od ? u2h(__builtin_amdgcn_perm(ypk1[(q8 + 3 + dh + 1) & 15], ypk1[(q8 + 3 + dh) & 15], 0x05040302u)) : u2h(ypk1[(q8 + 3 + dh) & 15]);
            f16x2 a0 = u2h(ypk1[q8 + 0]) * b0;
            f16x2 a1 = u2h(ypk1[q8 + 1]) * b1;
            f16x2 a2 = u2h(ypk1[q8 + 2]) * b2;
            f16x2 a3 = u2h(ypk1[q8 + 3]) * b3;
            f16x4 lo = __builtin_shufflevector(a0, a1, 0, 1, 2, 3);
            f16x4 hf = __builtin_shufflevector(a2, a3, 0, 1, 2, 3);
            f16x8 a  = __builtin_shufflevector(lo, hf, 0, 1, 2, 3, 4, 5, 6, 7);
            accB = __builtin_amdgcn_mfma_f32_32x32x16_f16(a, bfrag, accB, 0, 0, 0);
        }
    }

    // ---- 6) store: one base per tile, 16 constant-offset nt stores ----
    float* ob0 = out + (wrow + 4 * hi) * 32 + rl;
    float* ob1 = ob0 + 32 * 32;
    #pragma unroll
    for (int e = 0; e < 16; ++e) {
        __builtin_nontemporal_store(accA[e], ob0 + (e & 3) * 32 + (e >> 2) * 256);
        __builtin_nontemporal_store(accB[e], ob1 + (e & 3) * 32 + (e >> 2) * 256);
    }
}

extern "C" void kernel_launch(void* const* d_in, const int* in_sizes, int n_in,
                              void* d_out, int out_size, void* d_ws, size_t ws_size,
                              hipStream_t stream) {
    const float* x = (const float*)d_in[0];
    const float* W = (const float*)d_in[1];
    float* out = (float*)d_out;
    unsigned short* bt = (unsigned short*)d_ws;    // 33 KiB table

    prep_btab_sym<<<32, 256, 0, stream>>>(W, bt);
    int nrows = in_sizes[0] / 32;          // 262144
    int grid  = nrows / 256;               // 1024 blocks x 256 thr (2 tiles/wave)
    quadform_kernel<<<grid, 256, 0, stream>>>(x, (const uint4*)bt, out);
}

// Round 23
// 23.333 us; speedup vs baseline: 1.3382x; 1.0633x over previous
//
#include <hip/hip_runtime.h>

// out[n,k] = sum_{i,j} x[n,i] * W[k,i,j] * x[n,j]   (N=262144 rows, D=32)
// R23 = R17 (best, 22.8us) + ASYNC BTAB COPY via global_load_lds (width=16).
// At (1024,8) the prologue wants x-loads (32 regs) + btab staging (20 regs)
// live at once under a 64-reg cap -> compiler serializes the load streams.
// global_load_lds makes the 33KB table copy 3 zero-register async DMA
// instructions, issued AFTER the x loads (vmcnt ordering: waiting on older
// x-loads doesn't drain newer lds-DMAs), completing under the pack phase,
// drained by the existing __syncthreads. Copy order is linear in lane order
// (wave-uniform base + lane*16), matching the HW layout requirement.
// Everything else byte-identical to R17 (absmax 0.25).
//
// Algorithm: symmetrized circular-diagonal GEMM. p = d*32+i, d=0..16,
// z[n,p] = x[n,i]*x[n,(i+d)&31], Wf[p,k] = W[k,i,j]+W[k,j,i] (d=0 diag,
// d=16 half), K = 528 = 33 MFMA steps of v_mfma_f32_32x32x16_f16.

typedef _Float16 f16x2 __attribute__((ext_vector_type(2)));
typedef _Float16 f16x4 __attribute__((ext_vector_type(4)));
typedef _Float16 f16x8 __attribute__((ext_vector_type(8)));
typedef float    f32x16 __attribute__((ext_vector_type(16)));

static __device__ __forceinline__ unsigned int pk2_f16(float lo, float hi) {
    return __builtin_bit_cast(unsigned int, __builtin_amdgcn_cvt_pkrtz(lo, hi));
}
static __device__ __forceinline__ f16x2 u2h(unsigned int u) {
    return __builtin_bit_cast(f16x2, u);
}
static __device__ __forceinline__ unsigned short f16b(float f) {
    _Float16 h = (_Float16)f;
    return __builtin_bit_cast(unsigned short, h);
}
static __device__ __forceinline__ void gload_lds16(const void* g, void* l) {
    __builtin_amdgcn_global_load_lds(
        (const __attribute__((address_space(1))) void*)g,
        (__attribute__((address_space(3))) void*)l, 16, 0, 0);
}

// ---- prep (R16): one block per k; stage W_k in LDS coalesced, gather ----
__global__ __launch_bounds__(256)
void prep_btab_sym(const float* __restrict__ W, unsigned short* __restrict__ bt) {
    __shared__ float Wlds[1024];                    // 4 KiB = W[k,:,:]
    const int k = blockIdx.x;                       // 0..31
    const int t = threadIdx.x;
    {
        const float4* src = (const float4*)(W + k * 1024);
        ((float4*)Wlds)[t] = src[t];
    }
    __syncthreads();
    if (t < 66) {                                   // 33 n x 2 l-halves
        int n  = t >> 1;
        int lh = t & 1;                             // l = k + lh*32
        int d  = (n == 32) ? 16 : (n >> 1);
        int q  = (n == 32) ? 0  : (n & 1);
        unsigned short v[8];
        #pragma unroll
        for (int b = 0; b < 8; ++b) {
            int i = q * 16 + lh * 8 + b;
            int j = (i + d) & 31;
            float s = (d == 0) ? Wlds[i * 32 + i]
                               : Wlds[i * 32 + j] + Wlds[j * 32 + i];
            v[b] = f16b(s);
        }
        uint4 pk;
        pk.x = (unsigned int)v[0] | ((unsigned int)v[1] << 16);
        pk.y = (unsigned int)v[2] | ((unsigned int)v[3] << 16);
        pk.z = (unsigned int)v[4] | ((unsigned int)v[5] << 16);
        pk.w = (unsigned int)v[6] | ((unsigned int)v[7] << 16);
        ((uint4*)bt)[n * 64 + k + lh * 32] = pk;
    }
}

#define XS 20   // u32 per staged row (16 used + 4 pad -> bank spread)

__global__ __launch_bounds__(1024, 8)
void quadform_kernel(const float* __restrict__ x,
                     const unsigned short* __restrict__ bt_ws,
                     float* __restrict__ out) {
    __shared__ __align__(16) unsigned short btab[33 * 64 * 8];   // 33792 B
    __shared__ __align__(16) unsigned int   xstage[512 * XS];    // 40960 B

    const int tid  = threadIdx.x;
    const int lane = tid & 63;
    const int wave = tid >> 6;
    const int hi   = lane >> 5;
    const int rl   = lane & 31;
    const long blockrow = (long)blockIdx.x * 512;
    const long wrow = blockrow + wave * 32;         // this wave's 32 rows

    // ---- 1) issue coalesced x loads (HBM, slow - first) ----
    const float4* xsrc = (const float4*)(x + blockrow * 32);
    float4 xg0 = xsrc[tid];
    float4 xg1 = xsrc[1024 + tid];
    float4 xg2 = xsrc[2048 + tid];
    float4 xg3 = xsrc[3072 + tid];

    // ---- 2) btab copy: 3 async zero-register DMA (global -> LDS) ----
    {
        const uint4* bsrc = (const uint4*)bt_ws;
        uint4* bdst = (uint4*)btab;
        gload_lds16(bsrc + tid,        bdst + tid);
        gload_lds16(bsrc + 1024 + tid, bdst + 1024 + tid);
        if (tid < 64) gload_lds16(bsrc + 2048 + tid, bdst + 2048 + tid);
    }

    // ---- 3) pack + stage x (waits only on x loads; DMA continues) ----
    #pragma unroll
    for (int c = 0; c < 4; ++c) {
        float4 v = (c == 0) ? xg0 : (c == 1) ? xg1 : (c == 2) ? xg2 : xg3;
        int idx = c * 1024 + tid;                   // float4 index 0..4095
        int row = idx >> 3;                         // 8 float4 per row
        int sub = idx & 7;
        uint2 w2;
        w2.x = pk2_f16(v.x, v.y);
        w2.y = pk2_f16(v.z, v.w);
        *(uint2*)&xstage[row * XS + sub * 2] = w2;
    }
    __syncthreads();   // drains vmcnt (x + DMA) and lgkmcnt

    // ---- read own row from stage, pre-rotate by hi*4 (static indices) ----
    unsigned int ypk[16];
    {
        unsigned int xpk[16];
        const unsigned int* xr = &xstage[(wave * 32 + rl) * XS];
        #pragma unroll
        for (int c = 0; c < 4; ++c) {
            uint4 v = *(const uint4*)(xr + c * 4);
            xpk[c * 4 + 0] = v.x;
            xpk[c * 4 + 1] = v.y;
            xpk[c * 4 + 2] = v.z;
            xpk[c * 4 + 3] = v.w;
        }
        #pragma unroll
        for (int c = 0; c < 16; ++c)
            ypk[c] = hi ? xpk[(c + 4) & 15] : xpk[c];
    }

    f32x16 acc;
    #pragma unroll
    for (int e = 0; e < 16; ++e) acc[e] = 0.0f;

    // ---- K loop: 33 steps (17 circular diagonals), fully unrolled, SSA ----
    #pragma unroll
    for (int s = 0; s < 33; ++s) {
        const int d   = (s == 32) ? 16 : (s >> 1);
        const int q8  = ((s == 32) ? 0 : (s & 1)) * 8;
        const int dh  = d >> 1;
        const bool od = (d & 1) != 0;
        f16x8 bfrag = *(const f16x8*)(&btab[(s * 64 + lane) * 8]);

        f16x2 b0 = od ? u2h(__builtin_amdgcn_perm(ypk[(q8 + 0 + dh + 1) & 15], ypk[(q8 + 0 + dh) & 15], 0x05040302u)) : u2h(ypk[(q8 + 0 + dh) & 15]);
        f16x2 b1 = od ? u2h(__builtin_amdgcn_perm(ypk[(q8 + 1 + dh + 1) & 15], ypk[(q8 + 1 + dh) & 15], 0x05040302u)) : u2h(ypk[(q8 + 1 + dh) & 15]);
        f16x2 b2 = od ? u2h(__builtin_amdgcn_perm(ypk[(q8 + 2 + dh + 1) & 15], ypk[(q8 + 2 + dh) & 15], 0x05040302u)) : u2h(ypk[(q8 + 2 + dh) & 15]);
        f16x2 b3 = od ? u2h(__builtin_amdgcn_perm(ypk[(q8 + 3 + dh + 1) & 15], ypk[(q8 + 3 + dh) & 15], 0x05040302u)) : u2h(ypk[(q8 + 3 + dh) & 15]);
        f16x2 a0 = u2h(ypk[q8 + 0]) * b0;
        f16x2 a1 = u2h(ypk[q8 + 1]) * b1;
        f16x2 a2 = u2h(ypk[q8 + 2]) * b2;
        f16x2 a3 = u2h(ypk[q8 + 3]) * b3;
        f16x4 lo = __builtin_shufflevector(a0, a1, 0, 1, 2, 3);
        f16x4 hf = __builtin_shufflevector(a2, a3, 0, 1, 2, 3);
        f16x8 a  = __builtin_shufflevector(lo, hf, 0, 1, 2, 3, 4, 5, 6, 7);
        acc = __builtin_amdgcn_mfma_f32_32x32x16_f16(a, bfrag, acc, 0, 0, 0);
    }

    // ---- store: one base, 16 constant-offset nontemporal stores ----
    float* ob = out + (wrow + 4 * hi) * 32 + rl;
    #pragma unroll
    for (int e = 0; e < 16; ++e)
        __builtin_nontemporal_store(acc[e], ob + (e & 3) * 32 + (e >> 2) * 256);
}

extern "C" void kernel_launch(void* const* d_in, const int* in_sizes, int n_in,
                              void* d_out, int out_size, void* d_ws, size_t ws_size,
                              hipStream_t stream) {
    const float* x = (const float*)d_in[0];
    const float* W = (const float*)d_in[1];
    float* out = (float*)d_out;
    unsigned short* bt = (unsigned short*)d_ws;    // 33 KiB table

    prep_btab_sym<<<32, 256, 0, stream>>>(W, bt);
    int nrows = in_sizes[0] / 32;          // 262144
    int grid  = nrows / 512;               // 512 blocks x 1024 thr
    quadform_kernel<<<grid, 1024, 0, stream>>>(x, bt, out);
}

// Round 24
// 22.671 us; speedup vs baseline: 1.3774x; 1.0292x over previous
//
#include <hip/hip_runtime.h>

// out[n,k] = sum_{i,j} x[n,i] * W[k,i,j] * x[n,j]   (N=262144 rows, D=32)
// R24 = R17 VERBATIM (session best, 22.83us, absmax 0.25; tied by R19).
// Reverting R23's async-DMA btab copy (23.3us, falsification #13).
//
// Why this structure won (history): f16 packed datapath (R4, -19us vs bf16
// scalar-cvt), symmetrized circular-diagonal GEMM K=1024->528 (R12/R14),
// occupancy to 32 waves/CU via 1-tile/wave ~<=64 regs (R14/R15), one-time
// prep kernel for the Wsym f16 fragment table (R12/R16), COALESCED x via
// LDS bounce (R17, -3.9us), folded nontemporal stores (R16), 1024-thr
// blocks amortizing the btab copy (R17).
// Falsified alternatives (13): spill theories, bt-in-L2(x2), bt-in-regs,
// barrier-free, phase pipelines(x3), block stagger, I$, TLP, occupancy
// forcing, async DMA copy. All trade to ~22.8-25us -> structural plateau:
// mandatory HBM 8-10.6us + partially-overlapped on-CU 5-9us + prep/graph
// 2-4us + ramp/drain 3-4us.
//
// Algorithm: p = d*32+i (d=0..16), z[n,p] = x[n,i]*x[n,(i+d)&31],
// Wf[p,k] = W[k,i,j]+W[k,j,i] (d=0 diag; d=16 i<16 only). Each unordered
// (i,j) once -> K = 528 = 33 steps of v_mfma_f32_32x32x16_f16, fp32 acc.

typedef _Float16 f16x2 __attribute__((ext_vector_type(2)));
typedef _Float16 f16x4 __attribute__((ext_vector_type(4)));
typedef _Float16 f16x8 __attribute__((ext_vector_type(8)));
typedef float    f32x16 __attribute__((ext_vector_type(16)));

static __device__ __forceinline__ unsigned int pk2_f16(float lo, float hi) {
    return __builtin_bit_cast(unsigned int, __builtin_amdgcn_cvt_pkrtz(lo, hi));
}
static __device__ __forceinline__ f16x2 u2h(unsigned int u) {
    return __builtin_bit_cast(f16x2, u);
}
static __device__ __forceinline__ unsigned short f16b(float f) {
    _Float16 h = (_Float16)f;
    return __builtin_bit_cast(unsigned short, h);
}

// ---- prep: one block per k; stage W_k in LDS coalesced, gather Wsym ----
__global__ __launch_bounds__(256)
void prep_btab_sym(const float* __restrict__ W, unsigned short* __restrict__ bt) {
    __shared__ float Wlds[1024];                    // 4 KiB = W[k,:,:]
    const int k = blockIdx.x;                       // 0..31
    const int t = threadIdx.x;
    {
        const float4* src = (const float4*)(W + k * 1024);
        ((float4*)Wlds)[t] = src[t];
    }
    __syncthreads();
    if (t < 66) {                                   // 33 n x 2 l-halves
        int n  = t >> 1;
        int lh = t & 1;                             // l = k + lh*32
        int d  = (n == 32) ? 16 : (n >> 1);
        int q  = (n == 32) ? 0  : (n & 1);
        unsigned short v[8];
        #pragma unroll
        for (int b = 0; b < 8; ++b) {
            int i = q * 16 + lh * 8 + b;
            int j = (i + d) & 31;
            float s = (d == 0) ? Wlds[i * 32 + i]
                               : Wlds[i * 32 + j] + Wlds[j * 32 + i];
            v[b] = f16b(s);
        }
        uint4 pk;
        pk.x = (unsigned int)v[0] | ((unsigned int)v[1] << 16);
        pk.y = (unsigned int)v[2] | ((unsigned int)v[3] << 16);
        pk.z = (unsigned int)v[4] | ((unsigned int)v[5] << 16);
        pk.w = (unsigned int)v[6] | ((unsigned int)v[7] << 16);
        ((uint4*)bt)[n * 64 + k + lh * 32] = pk;
    }
}

#define XS 20   // u32 per staged row (16 used + 4 pad -> bank spread)

__global__ __launch_bounds__(1024, 8)
void quadform_kernel(const float* __restrict__ x,
                     const unsigned short* __restrict__ bt_ws,
                     float* __restrict__ out) {
    __shared__ __align__(16) unsigned short btab[33 * 64 * 8];   // 33792 B
    __shared__ __align__(16) unsigned int   xstage[512 * XS];    // 40960 B

    const int tid  = threadIdx.x;
    const int lane = tid & 63;
    const int wave = tid >> 6;
    const int hi   = lane >> 5;
    const int rl   = lane & 31;
    const long blockrow = (long)blockIdx.x * 512;
    const long wrow = blockrow + wave * 32;         // this wave's 32 rows

    // ---- 1) issue coalesced x loads (HBM, slow - first) ----
    const float4* xsrc = (const float4*)(x + blockrow * 32);
    float4 xg0 = xsrc[tid];
    float4 xg1 = xsrc[1024 + tid];
    float4 xg2 = xsrc[2048 + tid];
    float4 xg3 = xsrc[3072 + tid];

    // ---- 2) issue btab loads (L2, fast) ----
    const uint4* bsrc = (const uint4*)bt_ws;
    uint4 b0 = bsrc[tid];
    uint4 b1 = bsrc[1024 + tid];
    uint4 b2;
    if (tid < 64) b2 = bsrc[2048 + tid];

    // ---- 3) pack + stage x (waits only on x loads) ----
    #pragma unroll
    for (int c = 0; c < 4; ++c) {
        float4 v = (c == 0) ? xg0 : (c == 1) ? xg1 : (c == 2) ? xg2 : xg3;
        int idx = c * 1024 + tid;                   // float4 index 0..4095
        int row = idx >> 3;                         // 8 float4 per row
        int sub = idx & 7;
        uint2 w2;
        w2.x = pk2_f16(v.x, v.y);
        w2.y = pk2_f16(v.z, v.w);
        *(uint2*)&xstage[row * XS + sub * 2] = w2;
    }
    // ---- 4) write btab ----
    {
        uint4* dst = (uint4*)btab;
        dst[tid]        = b0;
        dst[1024 + tid] = b1;
        if (tid < 64) dst[2048 + tid] = b2;
    }
    __syncthreads();

    // ---- read own row from stage, pre-rotate by hi*4 (static indices) ----
    unsigned int ypk[16];
    {
        unsigned int xpk[16];
        const unsigned int* xr = &xstage[(wave * 32 + rl) * XS];
        #pragma unroll
        for (int c = 0; c < 4; ++c) {
            uint4 v = *(const uint4*)(xr + c * 4);
            xpk[c * 4 + 0] = v.x;
            xpk[c * 4 + 1] = v.y;
            xpk[c * 4 + 2] = v.z;
            xpk[c * 4 + 3] = v.w;
        }
        #pragma unroll
        for (int c = 0; c < 16; ++c)
            ypk[c] = hi ? xpk[(c + 4) & 15] : xpk[c];
    }

    f32x16 acc;
    #pragma unroll
    for (int e = 0; e < 16; ++e) acc[e] = 0.0f;

    // ---- K loop: 33 steps (17 circular diagonals), fully unrolled, SSA ----
    #pragma unroll
    for (int s = 0; s < 33; ++s) {
        const int d   = (s == 32) ? 16 : (s >> 1);
        const int q8  = ((s == 32) ? 0 : (s & 1)) * 8;
        const int dh  = d >> 1;
        const bool od = (d & 1) != 0;
        f16x8 bfrag = *(const f16x8*)(&btab[(s * 64 + lane) * 8]);

        f16x2 b0 = od ? u2h(__builtin_amdgcn_perm(ypk[(q8 + 0 + dh + 1) & 15], ypk[(q8 + 0 + dh) & 15], 0x05040302u)) : u2h(ypk[(q8 + 0 + dh) & 15]);
        f16x2 b1 = od ? u2h(__builtin_amdgcn_perm(ypk[(q8 + 1 + dh + 1) & 15], ypk[(q8 + 1 + dh) & 15], 0x05040302u)) : u2h(ypk[(q8 + 1 + dh) & 15]);
        f16x2 b2 = od ? u2h(__builtin_amdgcn_perm(ypk[(q8 + 2 + dh + 1) & 15], ypk[(q8 + 2 + dh) & 15], 0x05040302u)) : u2h(ypk[(q8 + 2 + dh) & 15]);
        f16x2 b3 = od ? u2h(__builtin_amdgcn_perm(ypk[(q8 + 3 + dh + 1) & 15], ypk[(q8 + 3 + dh) & 15], 0x05040302u)) : u2h(ypk[(q8 + 3 + dh) & 15]);
        f16x2 a0 = u2h(ypk[q8 + 0]) * b0;
        f16x2 a1 = u2h(ypk[q8 + 1]) * b1;
        f16x2 a2 = u2h(ypk[q8 + 2]) * b2;
        f16x2 a3 = u2h(ypk[q8 + 3]) * b3;
        f16x4 lo = __builtin_shufflevector(a0, a1, 0, 1, 2, 3);
        f16x4 hf = __builtin_shufflevector(a2, a3, 0, 1, 2, 3);
        f16x8 a  = __builtin_shufflevector(lo, hf, 0, 1, 2, 3, 4, 5, 6, 7);
        acc = __builtin_amdgcn_mfma_f32_32x32x16_f16(a, bfrag, acc, 0, 0, 0);
    }

    // ---- store: one base, 16 constant-offset nontemporal stores ----
    float* ob = out + (wrow + 4 * hi) * 32 + rl;
    #pragma unroll
    for (int e = 0; e < 16; ++e)
        __builtin_nontemporal_store(acc[e], ob + (e & 3) * 32 + (e >> 2) * 256);
}

extern "C" void kernel_launch(void* const* d_in, const int* in_sizes, int n_in,
                              void* d_out, int out_size, void* d_ws, size_t ws_size,
                              hipStream_t stream) {
    const float* x = (const float*)d_in[0];
    const float* W = (const float*)d_in[1];
    float* out = (float*)d_out;
    unsigned short* bt = (unsigned short*)d_ws;    // 33 KiB table

    prep_btab_sym<<<32, 256, 0, stream>>>(W, bt);
    int nrows = in_sizes[0] / 32;          // 262144
    int grid  = nrows / 512;               // 512 blocks x 1024 thr
    quadform_kernel<<<grid, 1024, 0, stream>>>(x, bt, out);
}